// Round 14
// baseline (251.673 us; speedup 1.0000x reference)
//
#include <hip/hip_runtime.h>
#include <hip/hip_bf16.h>

typedef __hip_bfloat16 bf16;
typedef unsigned short ush;
typedef short s16x8 __attribute__((ext_vector_type(8)));
typedef ush u16x4 __attribute__((ext_vector_type(4)));
typedef float f32x4 __attribute__((ext_vector_type(4)));

#define DEV __device__ __forceinline__

DEV float rcp_f(float x) { return __builtin_amdgcn_rcpf(x); }
DEV float sigmoid_f(float x) { return rcp_f(1.f + __expf(-x)); }
DEV float tanh_f(float x) { return 1.f - 2.f * rcp_f(__expf(2.f * x) + 1.f); }

DEV float u2f(ush u) { unsigned int v = ((unsigned int)u) << 16; float f; __builtin_memcpy(&f, &v, 4); return f; }
DEV ush f2u(float f) { bf16 h = __float2bfloat16(f); ush u; __builtin_memcpy(&u, &h, 2); return u; }

DEV f32x4 MFMA(s16x8 a, s16x8 b, f32x4 c) {
  return __builtin_amdgcn_mfma_f32_16x16x32_bf16(a, b, c, 0, 0, 0);
}

DEV s16x8 z8() {
  s16x8 v;
  for (int z = 0; z < 8; ++z) v[z] = 0;
  return v;
}

// swizzled element index within a [rows][32] bf16 chunk: 16B blocks XOR'd by (row>>1)&3
DEV int swz_idx(int row, int kk) { return row * 32 + (((kk >> 3) ^ ((row >> 1) & 3)) << 3) + (kk & 7); }
DEV int swz_blk(int row, int blk) { return row * 32 + ((blk ^ ((row >> 1) & 3)) << 3); }

// ---------------------------------------------------------------------------
// N=4096 graphs, K=8 nodes, n_in=14, H=128, k=3 iters. Inputs fp32.
// xh:  [32768][144] bf16 = [towers(14), pad(2), h(128)]
// eh:  iteration-carry only (rows g*64 + i*9+1).
// gn_iter<FIRST,LAST> (512 blocks x 8 graphs): per-iteration fusion.
//   [FIRST: enc E_n MLP -> xh, then Ee MLP -> As_e] / [else: As_e from eh]
//   edge GRU (WIHe·xx^T 9ck + WTh·e^T 4ck, full-width BX staging, no inner
//   barriers) -> As_e in place (+eh if !LAST)
//   node GRU (BX staged once, 9 barrier-free MFMA rounds, WTu direct-global)
//   [LAST: per-block hsum/esum]
// Fusion laws learned: per-iteration kernels only (3-iter loop in one kernel
// spills ~0.5GB, R8/R11); 8-graph blocks are the sweet spot (R12); kernel
// duration ~= single-block critical path (R10/R12/R13), so the remaining
// wins are launch-count and prologue folds.
// ---------------------------------------------------------------------------

__global__ __launch_bounds__(256) void prep_all(
    const float* __restrict__ towers,
    const float* __restrict__ MWih, const float* __restrict__ MWhh,
    const float* __restrict__ UWih, const float* __restrict__ UWhh,
    const float* __restrict__ EnW1, const float* __restrict__ EnW2,
    const float* __restrict__ EeW1, const float* __restrict__ EeW2,
    const float* __restrict__ MBih, const float* __restrict__ MBhh,
    const float* __restrict__ UBih, const float* __restrict__ UBhh,
    const float* __restrict__ GWih, const float* __restrict__ GWhh,
    const float* __restrict__ GBih, const float* __restrict__ GBhh,
    ush* __restrict__ xh, ush* __restrict__ WIHe, ush* __restrict__ WTh,
    ush* __restrict__ WTu, ush* __restrict__ WBen1, ush* __restrict__ WBen2,
    ush* __restrict__ WBee1, ush* __restrict__ WBee2,
    float* __restrict__ biasM, float* __restrict__ biasU,
    float* __restrict__ WT_G, float* __restrict__ biasG)
{
  const int b = blockIdx.x, t = threadIdx.x;
  if (b < 512) {                        // xh towers: 4 elems/thread
    const int idx = b * 256 + t;        // 131072 threads
    const int row = idx >> 2, k0 = (idx & 3) * 4;
    u16x4 v;
    #pragma unroll
    for (int j = 0; j < 4; ++j) {
      const int kk = k0 + j;
      v[j] = f2u(kk < 14 ? towers[row * 14 + kk] : 0.f);
    }
    *(u16x4*)&xh[row * 144 + k0] = v;
  } else if (b < 944) {                 // WIHe: 9*384*32 linear (edge Wih)
    const int idx = (b - 512) * 256 + t;
    const int ck = idx / 12288, rem = idx % 12288, n = rem >> 5, kk = rem & 31;
    const int k = ck * 32 + kk;
    const int gate = n >> 7, c = n & 127;
    const int row = gate * 128 + c;
    int col = -1;
    if (k < 14)                    col = k;               // x_i
    else if (k >= 16 && k < 144)   col = 14 + (k - 16);   // h_i
    else if (k >= 144 && k < 158)  col = 142 + (k - 144); // x_j
    else if (k >= 160)             col = 156 + (k - 160); // h_j
    WIHe[idx] = f2u((col >= 0) ? MWih[row * 284 + col] : 0.f);
  } else if (b < 1136) {                // WTh: 4*384*32 linear
    const int idx = (b - 944) * 256 + t;
    const int ck = idx / 12288, rem = idx % 12288, n = rem >> 5, kk = rem & 31;
    const int g = n >> 7, c = n & 127;
    WTh[idx] = f2u(MWhh[(g * 128 + c) * 128 + ck * 32 + kk]);
  } else if (b < 1712) {                // WTu: 9*512*32 swizzled
    const int idx = (b - 1136) * 256 + t;
    const int ck = idx >> 14, n = (idx >> 5) & 511, kk = idx & 31;
    const int k = ck * 32 + kk, gate = n >> 7, c = n & 127;
    float w = 0.f;
    const int row = (gate == 0) ? c : (gate == 1) ? 128 + c : 256 + c;
    if (k < 160) {
      int col = -1;
      if (k < 16)        { if (k < 14) col = k; }
      else if (k < 144)  col = 14 + (k - 16);
      if (gate != 3 && col >= 0) w = UWih[row * 142 + col];
    } else {
      if (gate != 2) w = UWhh[row * 128 + (k - 160)];
    }
    WTu[ck * 16384 + swz_idx(n, kk)] = f2u(w);
  } else if (b < 1728) {                // WBen1: 128x32 linear
    const int idx = (b - 1712) * 256 + t;
    const int n = (idx >> 5) & 127, kk = idx & 31;
    WBen1[idx] = f2u(kk < 14 ? EnW1[n * 14 + kk] : 0.f);
  } else if (b < 1792) {                // WBen2: 4*128*32 linear
    const int idx = (b - 1728) * 256 + t;
    const int ck = idx >> 12, n = (idx >> 5) & 127, kk = idx & 31;
    WBen2[idx] = f2u(EnW2[n * 128 + ck * 32 + kk]);
  } else if (b < 1808) {                // WBee1: 128x32 pair linear
    const int idx = (b - 1792) * 256 + t;
    const int n = (idx >> 5) & 127, kk = idx & 31;
    int col = (kk < 16) ? (kk < 14 ? kk : -1) : (kk < 30 ? 14 + (kk - 16) : -1);
    WBee1[idx] = f2u(col >= 0 ? EeW1[n * 28 + col] : 0.f);
    (void)n;
  } else if (b < 1872) {                // WBee2: 4*128*32 linear
    const int idx = (b - 1808) * 256 + t;
    const int ck = idx >> 12, n = (idx >> 5) & 127, kk = idx & 31;
    WBee2[idx] = f2u(EeW2[n * 128 + ck * 32 + kk]);
  } else if (b < 1874) {                // biasM [4 gates][128]
    const int idx = (b - 1872) * 256 + t;
    const int g = idx >> 7, c = idx & 127;
    float v;
    if (g == 0)      v = MBih[c] + MBhh[c];
    else if (g == 1) v = MBih[128 + c] + MBhh[128 + c];
    else if (g == 2) v = MBih[256 + c];
    else             v = MBhh[256 + c];
    biasM[idx] = v;
  } else if (b < 1876) {                // biasU
    const int idx = (b - 1874) * 256 + t;
    const int g = idx >> 7, c = idx & 127;
    float v;
    if (g == 0)      v = UBih[c] + UBhh[c];
    else if (g == 1) v = UBih[128 + c] + UBhh[128 + c];
    else if (g == 2) v = UBih[256 + c];
    else             v = UBhh[256 + c];
    biasU[idx] = v;
  } else if (b < 2644) {                // WT_G interleaved fp32: 384*512
    const int idx = (b - 1876) * 256 + t;
    const int kc = idx >> 9, cg = (idx >> 2) & 127, gate = idx & 3;
    const int row = (gate == 0) ? cg : (gate == 1) ? cg + 128 : cg + 256;
    float v = 0.f;
    if (kc < 256) { if (gate != 3) v = GWih[row * 256 + kc]; }
    else          { if (gate != 2) v = GWhh[row * 128 + (kc - 256)]; }
    WT_G[idx] = v;
  } else {                              // biasG
    const int idx = (b - 2644) * 256 + t;
    const int cg = idx >> 2, gate = idx & 3;
    float v;
    if (gate == 0)      v = GBih[cg] + GBhh[cg];
    else if (gate == 1) v = GBih[cg + 128] + GBhh[cg + 128];
    else if (gate == 2) v = GBih[cg + 256];
    else                v = GBhh[cg + 256];
    biasG[idx] = v;
  }
}

// ---------------------------------------------------------------------------
// E_n MLP (64 node rows) -> h into xh. SC: A1 [0,1024) | Z1 [1024,9216).
// ---------------------------------------------------------------------------
DEV void enc_body(ush* SC, ush* __restrict__ xh,
                  const ush* __restrict__ WB1, const float* __restrict__ b1,
                  const ush* __restrict__ WB2, const float* __restrict__ b2,
                  int rowBase, int t)
{
  ush* A1 = SC;
  ush* Z1 = SC + 1024;
  const int lane = t & 63, w = t >> 6;
  const int quad = lane >> 4, l15 = lane & 15;

  {
    const int gm = t >> 2, gb = t & 3, grow = rowBase + gm;
    s16x8 v = z8();
    if (gb < 2) v = *(const s16x8*)(xh + grow * 144 + gb * 8);
    *(s16x8*)&A1[swz_blk(gm, gb)] = v;
  }
  __syncthreads();

  s16x8 af[4];
  #pragma unroll
  for (int rt = 0; rt < 4; ++rt)
    af[rt] = *(const s16x8*)&A1[swz_blk(rt * 16 + l15, quad)];
  f32x4 acc1[4][2];
  #pragma unroll
  for (int rt = 0; rt < 4; ++rt)
    #pragma unroll
    for (int ct = 0; ct < 2; ++ct) {
      #pragma unroll
      for (int q = 0; q < 4; ++q) acc1[rt][ct][q] = 0.f;
    }
  #pragma unroll
  for (int ct = 0; ct < 2; ++ct) {
    const int n = w * 32 + ct * 16 + l15;
    const s16x8 bf = *(const s16x8*)&WB1[n * 32 + quad * 8];
    #pragma unroll
    for (int rt = 0; rt < 4; ++rt) acc1[rt][ct] = MFMA(af[rt], bf, acc1[rt][ct]);
  }
  #pragma unroll
  for (int ct = 0; ct < 2; ++ct) {
    const int col = w * 32 + ct * 16 + l15;
    const int kk = col & 31;
    #pragma unroll
    for (int rt = 0; rt < 4; ++rt) {
      #pragma unroll
      for (int q = 0; q < 4; ++q) {
        const int m = rt * 16 + quad * 4 + q;
        Z1[w * 2048 + swz_idx(m, kk)] = f2u(tanh_f(acc1[rt][ct][q] + b1[col]));
      }
    }
  }
  __syncthreads();

  f32x4 acc2[4][2];
  #pragma unroll
  for (int rt = 0; rt < 4; ++rt)
    #pragma unroll
    for (int ct = 0; ct < 2; ++ct) {
      #pragma unroll
      for (int q = 0; q < 4; ++q) acc2[rt][ct][q] = 0.f;
    }
  for (int ck2 = 0; ck2 < 4; ++ck2) {
    #pragma unroll
    for (int rt = 0; rt < 4; ++rt)
      af[rt] = *(const s16x8*)&Z1[ck2 * 2048 + swz_blk(rt * 16 + l15, quad)];
    #pragma unroll
    for (int ct = 0; ct < 2; ++ct) {
      const int n = w * 32 + ct * 16 + l15;
      const s16x8 bf = *(const s16x8*)&WB2[(ck2 * 128 + n) * 32 + quad * 8];
      #pragma unroll
      for (int rt = 0; rt < 4; ++rt) acc2[rt][ct] = MFMA(af[rt], bf, acc2[rt][ct]);
    }
  }

  #pragma unroll
  for (int ct = 0; ct < 2; ++ct) {
    const int col = w * 32 + ct * 16 + l15;
    #pragma unroll
    for (int rt = 0; rt < 4; ++rt) {
      #pragma unroll
      for (int q = 0; q < 4; ++q) {
        const int r = rt * 16 + quad * 4 + q;
        xh[(rowBase + r) * 144 + 16 + col] = f2u(tanh_f(acc2[rt][ct][q] + b2[col]));
      }
    }
  }
}

// ---------------------------------------------------------------------------
// Ee MLP on the (i,i+1) pairs -> e^0 into As_e (B-operand layout).
// SC: A1 [0,1024) | Z1 [1024,9216).
// ---------------------------------------------------------------------------
DEV void ee_body(ush* As_e, ush* SC, const ush* __restrict__ xh,
                 const ush* __restrict__ WB1, const float* __restrict__ b1,
                 const ush* __restrict__ WB2, const float* __restrict__ b2,
                 int G0, int t)
{
  ush* A1 = SC;
  ush* Z1 = SC + 1024;
  const int lane = t & 63, w = t >> 6;
  const int quad = lane >> 4, l15 = lane & 15;

  {
    const int gm = t >> 2, gb = t & 3;
    const int gg = gm >> 3, i = gm & 7;
    const int xi = (G0 + gg) * 8 + i;
    const int xj = (i < 7) ? xi + 1 : xi;
    const s16x8 v = (gb < 2) ? *(const s16x8*)(xh + xi * 144 + gb * 8)
                             : *(const s16x8*)(xh + xj * 144 + (gb - 2) * 8);
    *(s16x8*)&A1[swz_blk(gm, gb)] = v;
  }
  __syncthreads();

  s16x8 af[4];
  #pragma unroll
  for (int rt = 0; rt < 4; ++rt)
    af[rt] = *(const s16x8*)&A1[swz_blk(rt * 16 + l15, quad)];
  f32x4 acc1[4][2];
  #pragma unroll
  for (int rt = 0; rt < 4; ++rt)
    #pragma unroll
    for (int ct = 0; ct < 2; ++ct) {
      #pragma unroll
      for (int q = 0; q < 4; ++q) acc1[rt][ct][q] = 0.f;
    }
  #pragma unroll
  for (int ct = 0; ct < 2; ++ct) {
    const int n = w * 32 + ct * 16 + l15;
    const s16x8 bf = *(const s16x8*)&WB1[n * 32 + quad * 8];
    #pragma unroll
    for (int rt = 0; rt < 4; ++rt) acc1[rt][ct] = MFMA(af[rt], bf, acc1[rt][ct]);
  }
  #pragma unroll
  for (int ct = 0; ct < 2; ++ct) {
    const int col = w * 32 + ct * 16 + l15;
    const int kk = col & 31;
    #pragma unroll
    for (int rt = 0; rt < 4; ++rt) {
      #pragma unroll
      for (int q = 0; q < 4; ++q) {
        const int m = rt * 16 + quad * 4 + q;
        Z1[w * 2048 + swz_idx(m, kk)] = f2u(tanh_f(acc1[rt][ct][q] + b1[col]));
      }
    }
  }
  __syncthreads();

  f32x4 acc2[4][2];
  #pragma unroll
  for (int rt = 0; rt < 4; ++rt)
    #pragma unroll
    for (int ct = 0; ct < 2; ++ct) {
      #pragma unroll
      for (int q = 0; q < 4; ++q) acc2[rt][ct][q] = 0.f;
    }
  for (int ck2 = 0; ck2 < 4; ++ck2) {
    #pragma unroll
    for (int rt = 0; rt < 4; ++rt)
      af[rt] = *(const s16x8*)&Z1[ck2 * 2048 + swz_blk(rt * 16 + l15, quad)];
    #pragma unroll
    for (int ct = 0; ct < 2; ++ct) {
      const int n = w * 32 + ct * 16 + l15;
      const s16x8 bf = *(const s16x8*)&WB2[(ck2 * 128 + n) * 32 + quad * 8];
      #pragma unroll
      for (int rt = 0; rt < 4; ++rt) acc2[rt][ct] = MFMA(af[rt], bf, acc2[rt][ct]);
    }
  }
  #pragma unroll
  for (int ct = 0; ct < 2; ++ct) {
    const int col = w * 32 + ct * 16 + l15;
    #pragma unroll
    for (int rt = 0; rt < 4; ++rt) {
      #pragma unroll
      for (int q = 0; q < 4; ++q) {
        const int r = rt * 16 + quad * 4 + q;
        As_e[(col >> 5) * 2048 + swz_idx(r, col & 31)] = f2u(tanh_f(acc2[rt][ct][q] + b2[col]));
      }
    }
  }
}

// ---------------------------------------------------------------------------
// Edge GRU core: full-width xx staged to BX ONCE, then 9 MFMA rounds with no
// barriers; h phase from As_e; in-place As_e update; eh carry unless LAST.
// ---------------------------------------------------------------------------
template<int LAST>
DEV void edge_core(ush* As_e, ush* BX, ush* __restrict__ eh,
                   const ush* __restrict__ WIHe, const ush* __restrict__ WTh,
                   const float* __restrict__ biasM,
                   const ush* __restrict__ xh, int G0, int t)
{
  const int lane = t & 63, w = t >> 6;
  const int quad = lane >> 4, l15 = lane & 15;
  const int ko = quad * 8;

  f32x4 accR[2][4], accZ[2][4], accN1[2][4], accN2[2][4];
  #pragma unroll
  for (int mt = 0; mt < 2; ++mt)
    #pragma unroll
    for (int nt = 0; nt < 4; ++nt) {
      #pragma unroll
      for (int q = 0; q < 4; ++q) { accR[mt][nt][q] = 0.f; accZ[mt][nt][q] = 0.f; accN1[mt][nt][q] = 0.f; accN2[mt][nt][q] = 0.f; }
    }

  // stage ALL 9 xx chunks (K=288) into BX, one barrier
  {
    const int gm = t >> 2, gb = t & 3;
    const int gg = gm >> 3, i = gm & 7;
    const int xi = (G0 + gg) * 8 + i;
    const int xj = xi + ((i < 7) ? 1 : 0);
    #pragma unroll
    for (int ck = 0; ck < 9; ++ck) {
      const int k0 = ck * 32 + gb * 8;
      const s16x8 v = (k0 < 144) ? *(const s16x8*)(xh + xi * 144 + k0)
                                 : *(const s16x8*)(xh + xj * 144 + (k0 - 144));
      *(s16x8*)&BX[ck * 2048 + swz_blk(gm, gb)] = v;
    }
  }
  __syncthreads();

  // xx phase: 9 rounds, no barriers — compiler pipelines LDS + global loads
  #pragma unroll
  for (int ck = 0; ck < 9; ++ck) {
    s16x8 be[4];
    #pragma unroll
    for (int nt = 0; nt < 4; ++nt)
      be[nt] = *(const s16x8*)&BX[ck * 2048 + swz_blk(nt * 16 + l15, quad)];
    #pragma unroll
    for (int mt = 0; mt < 2; ++mt) {
      const int nb = w * 32 + mt * 16 + l15;
      const s16x8 aR = *(const s16x8*)&WIHe[(ck * 384 + nb) * 32 + ko];
      const s16x8 aZ = *(const s16x8*)&WIHe[(ck * 384 + 128 + nb) * 32 + ko];
      const s16x8 aN = *(const s16x8*)&WIHe[(ck * 384 + 256 + nb) * 32 + ko];
      #pragma unroll
      for (int nt = 0; nt < 4; ++nt) {
        accR[mt][nt]  = MFMA(aR, be[nt], accR[mt][nt]);
        accZ[mt][nt]  = MFMA(aZ, be[nt], accZ[mt][nt]);
        accN1[mt][nt] = MFMA(aN, be[nt], accN1[mt][nt]);
      }
    }
  }

  // h phase: K = 128 (4 chunks) from As_e, gates r, z, n2
  #pragma unroll
  for (int ck = 0; ck < 4; ++ck) {
    s16x8 be[4];
    #pragma unroll
    for (int nt = 0; nt < 4; ++nt)
      be[nt] = *(const s16x8*)&As_e[ck * 2048 + swz_blk(nt * 16 + l15, quad)];
    #pragma unroll
    for (int mt = 0; mt < 2; ++mt) {
      const int nb = w * 32 + mt * 16 + l15;
      const s16x8 aR = *(const s16x8*)&WTh[(ck * 384 + nb) * 32 + ko];
      const s16x8 aZ = *(const s16x8*)&WTh[(ck * 384 + 128 + nb) * 32 + ko];
      const s16x8 aN = *(const s16x8*)&WTh[(ck * 384 + 256 + nb) * 32 + ko];
      #pragma unroll
      for (int nt = 0; nt < 4; ++nt) {
        accR[mt][nt]  = MFMA(aR, be[nt], accR[mt][nt]);
        accZ[mt][nt]  = MFMA(aZ, be[nt], accZ[mt][nt]);
        accN2[mt][nt] = MFMA(aN, be[nt], accN2[mt][nt]);
      }
    }
  }

  __syncthreads();   // all h-phase As_e reads complete before in-place update

  // epilogue: biases + GRU; in-place As_e update (1:1 thread ownership),
  // eh carry-out for valid slots unless LAST.
  #pragma unroll
  for (int mt = 0; mt < 2; ++mt) {
    const int hc0 = w * 32 + mt * 16 + quad * 4;
    const int ck2 = hc0 >> 5, kkB = hc0 & 31;
    #pragma unroll
    for (int nt = 0; nt < 4; ++nt) {
      const int erow = nt * 16 + l15;
      const int gg = erow >> 3, i = erow & 7;
      ush* cell = &As_e[ck2 * 2048 + swz_blk(erow, kkB >> 3) + (kkB & 7)];
      const u16x4 hp4 = *(const u16x4*)cell;
      u16x4 ov;
      #pragma unroll
      for (int q = 0; q < 4; ++q) {
        const int c = hc0 + q;
        const float rg = sigmoid_f(accR[mt][nt][q] + biasM[c]);
        const float zg = sigmoid_f(accZ[mt][nt][q] + biasM[128 + c]);
        const float nn = tanh_f(accN1[mt][nt][q] + biasM[256 + c]
                                + rg * (accN2[mt][nt][q] + biasM[384 + c]));
        const float hp = u2f(hp4[q]);
        ov[q] = f2u(nn + zg * (hp - nn));
      }
      *(u16x4*)cell = ov;
      if (!LAST && i < 7)
        *(u16x4*)&eh[(size_t)((G0 + gg) * 64 + i * 9 + 1) * 128 + hc0] = ov;
    }
  }
}

// ---------------------------------------------------------------------------
// Node GRU: full 288-wide input staged to BX once, then 9 MFMA rounds with
// no barriers (WTu B direct-global); edges from As_e (LDS).
// ---------------------------------------------------------------------------
DEV void node_lds(const ush* As_e, ush* BX, ush* __restrict__ xh,
                  const ush* __restrict__ WT, const float* __restrict__ bias,
                  int rowBase, int t)
{
  constexpr int NCH = 9, XCH = 5;
  const int lane = t & 63, w = t >> 6;
  const int l15 = lane & 15, quad = lane >> 4;

  f32x4 accR[4][2], accZ[4][2], accN1[4][2], accN2[4][2];
  #pragma unroll
  for (int rt = 0; rt < 4; ++rt)
    #pragma unroll
    for (int s = 0; s < 2; ++s) {
      #pragma unroll
      for (int q = 0; q < 4; ++q) { accR[rt][s][q] = 0.f; accZ[rt][s][q] = 0.f; accN1[rt][s][q] = 0.f; accN2[rt][s][q] = 0.f; }
    }

  // stage ALL 9 input chunks into BX, one barrier
  {
    const int gm = t >> 2, gb = t & 3, grow = rowBase + gm;
    const int i = gm & 7;
    #pragma unroll
    for (int ck = 0; ck < NCH; ++ck) {
      const int k0 = ck * 32 + gb * 8;
      s16x8 v = z8();
      if (k0 < 16)       v = *(const s16x8*)(xh + grow * 144 + k0);
      else if (k0 < 144) {
        if (i < 7) {
          const int ke = k0 - 16;
          v = *(const s16x8*)&As_e[(ke >> 5) * 2048 + swz_blk(gm, (ke & 31) >> 3)];
        }
      } else if (k0 >= 160) {
        v = *(const s16x8*)(xh + grow * 144 + 16 + (k0 - 160));
      }
      *(s16x8*)&BX[ck * 2048 + swz_blk(gm, gb)] = v;
    }
  }
  __syncthreads();

  // 9 MFMA rounds, no barriers
  #pragma unroll
  for (int ck = 0; ck < NCH; ++ck) {
    const ush* Wc = WT + ck * 16384;
    s16x8 af[4];
    #pragma unroll
    for (int rt = 0; rt < 4; ++rt)
      af[rt] = *(const s16x8*)&BX[ck * 2048 + swz_blk(rt * 16 + l15, quad)];
    if (ck < XCH) {
      #pragma unroll
      for (int s = 0; s < 2; ++s) {
        const int nb = w * 32 + s * 16 + l15;
        const s16x8 bR = *(const s16x8*)&Wc[swz_blk(0 * 128 + nb, quad)];
        const s16x8 bZ = *(const s16x8*)&Wc[swz_blk(1 * 128 + nb, quad)];
        const s16x8 bN = *(const s16x8*)&Wc[swz_blk(2 * 128 + nb, quad)];
        #pragma unroll
        for (int rt = 0; rt < 4; ++rt) {
          accR[rt][s]  = MFMA(af[rt], bR, accR[rt][s]);
          accZ[rt][s]  = MFMA(af[rt], bZ, accZ[rt][s]);
          accN1[rt][s] = MFMA(af[rt], bN, accN1[rt][s]);
        }
      }
    } else {
      #pragma unroll
      for (int s = 0; s < 2; ++s) {
        const int nb = w * 32 + s * 16 + l15;
        const s16x8 bR = *(const s16x8*)&Wc[swz_blk(0 * 128 + nb, quad)];
        const s16x8 bZ = *(const s16x8*)&Wc[swz_blk(1 * 128 + nb, quad)];
        const s16x8 bN = *(const s16x8*)&Wc[swz_blk(3 * 128 + nb, quad)];
        #pragma unroll
        for (int rt = 0; rt < 4; ++rt) {
          accR[rt][s]  = MFMA(af[rt], bR, accR[rt][s]);
          accZ[rt][s]  = MFMA(af[rt], bZ, accZ[rt][s]);
          accN2[rt][s] = MFMA(af[rt], bN, accN2[rt][s]);
        }
      }
    }
  }

  #pragma unroll
  for (int s = 0; s < 2; ++s) {
    const int hcol = w * 32 + s * 16 + l15;
    const float bR = bias[hcol], bZ = bias[128 + hcol], bN1 = bias[256 + hcol], bN2 = bias[384 + hcol];
    #pragma unroll
    for (int rt = 0; rt < 4; ++rt) {
      #pragma unroll
      for (int q = 0; q < 4; ++q) {
        const int r = rt * 16 + quad * 4 + q;
        const int row = rowBase + r;
        const float hp = u2f(xh[row * 144 + 16 + hcol]);
        const float rg = sigmoid_f(accR[rt][s][q] + bR);
        const float zg = sigmoid_f(accZ[rt][s][q] + bZ);
        const float nn = tanh_f(accN1[rt][s][q] + bN1 + rg * (accN2[rt][s][q] + bN2));
        xh[row * 144 + 16 + hcol] = f2u(nn + zg * (hp - nn));
      }
    }
  }
}

// per-block readout: esum from As_e (final edges), hsum from xh (final h)
DEV void sums_body(const ush* As_e, const ush* __restrict__ xh,
                   float* __restrict__ hsum, float* __restrict__ esum,
                   int G0, int rowBase, int t)
{
  #pragma unroll
  for (int ii = 0; ii < 4; ++ii) {
    const int p = t + ii * 256;
    const int gg = p >> 7, hh = p & 127;
    float es = 0.f;
    #pragma unroll
    for (int i = 0; i < 7; ++i) {
      const int slot = gg * 8 + i;
      es += u2f(As_e[(hh >> 5) * 2048 + swz_idx(slot, hh & 31)]);
    }
    float hs = 0.f;
    #pragma unroll
    for (int i = 0; i < 8; ++i)
      hs += u2f(xh[(rowBase + gg * 8 + i) * 144 + 16 + hh]);
    hsum[(G0 + gg) * 128 + hh] = hs;
    esum[(G0 + gg) * 128 + hh] = es;
  }
}

// ---------------------------------------------------------------------------
// One fused GN iteration: [enc + Ee | eh load] -> edge GRU -> node GRU
// [-> sums]. LDS: As_e 8KB + BX 18KB = 26KB.
// ---------------------------------------------------------------------------
template<int FIRST, int LAST>
__global__ __launch_bounds__(256, 2) void gn_iter(
    ush* __restrict__ eh, ush* __restrict__ xh,
    const ush* __restrict__ WIHe, const ush* __restrict__ WTh,
    const float* __restrict__ biasM,
    const ush* __restrict__ WTu, const float* __restrict__ biasU,
    const ush* __restrict__ WBen1, const float* __restrict__ bEn1,
    const ush* __restrict__ WBen2, const float* __restrict__ bEn2,
    const ush* __restrict__ WBee1, const float* __restrict__ bEe1,
    const ush* __restrict__ WBee2, const float* __restrict__ bEe2,
    float* __restrict__ hsum, float* __restrict__ esum)
{
  __shared__ ush smem[26624];          // As_e [0,8192) | BX [8192,26624)
  ush* As_e = smem;
  ush* BX   = smem + 8192;
  const int t = threadIdx.x;
  const int G0 = blockIdx.x * 8, rowBase = blockIdx.x * 64;

  if (FIRST) {
    enc_body(BX, xh, WBen1, bEn1, WBen2, bEn2, rowBase, t);
    __syncthreads();                   // h in xh visible block-wide
    ee_body(As_e, BX, xh, WBee1, bEe1, WBee2, bEe2, G0, t);
  } else {
    const int gm = t >> 2, gb = t & 3;
    const int gg = gm >> 3, i = gm & 7;
    const ush* src = eh + (size_t)((G0 + gg) * 64 + i * 9 + 1) * 128;
    #pragma unroll
    for (int ck = 0; ck < 4; ++ck) {
      s16x8 v = z8();
      if (i < 7) v = *(const s16x8*)(src + ck * 32 + gb * 8);
      *(s16x8*)&As_e[ck * 2048 + swz_blk(gm, gb)] = v;
    }
  }
  __syncthreads();

  edge_core<LAST>(As_e, BX, eh, WIHe, WTh, biasM, xh, G0, t);
  __syncthreads();

  node_lds(As_e, BX, xh, WTu, biasU, rowBase, t);

  if (LAST) {
    __syncthreads();
    sums_body(As_e, xh, hsum, esum, G0, rowBase, t);
  }
}

// global GRU (h_prev = 0) fused with output head: 16 graphs per block.
__global__ __launch_bounds__(256) void gru_global_out(
    const float* __restrict__ hsum, const float* __restrict__ esum,
    const float* __restrict__ WT, const float* __restrict__ bias,
    const float* __restrict__ OW, const float* __restrict__ Ob,
    float* __restrict__ out)
{
  constexpr int KT = 384;
  __shared__ float4 ATl4[KT * 4];
  __shared__ float4 Bl4[16 * 128];
  __shared__ float gmat[16 * 128];
  __shared__ float red[16 * 4];
  float* ATl = (float*)ATl4;
  const int t = threadIdx.x;
  const int rowBase = blockIdx.x * 16;
  for (int idx = t; idx < KT * 16; idx += 256) {
    const int kc = idx >> 4, r = idx & 15, grow = rowBase + r;
    float v = 0.f;
    if (kc < 128)      v = hsum[grow * 128 + kc];
    else if (kc < 256) v = esum[grow * 128 + (kc - 128)];
    ATl[idx] = v;
  }
  const int c = t & 127, rh = t >> 7;
  float accR[8], accZ[8], accN1[8];
  #pragma unroll
  for (int rr = 0; rr < 8; ++rr) { accR[rr] = 0.f; accZ[rr] = 0.f; accN1[rr] = 0.f; }
  const float4* WT4 = (const float4*)WT;
  for (int ck = 0; ck < 16; ++ck) {
    __syncthreads();
    #pragma unroll
    for (int ii = 0; ii < 8; ++ii) { const int idx = t + ii * 256; Bl4[idx] = WT4[ck * 2048 + idx]; }
    __syncthreads();
    const int kb = ck * 16;
    #pragma unroll
    for (int kcl = 0; kcl < 16; ++kcl) {
      const float4 wv = Bl4[kcl * 128 + c];
      const float4 a0 = ATl4[(kb + kcl) * 4 + rh * 2];
      const float4 a1 = ATl4[(kb + kcl) * 4 + rh * 2 + 1];
      const float av[8] = {a0.x, a0.y, a0.z, a0.w, a1.x, a1.y, a1.z, a1.w};
      #pragma unroll
      for (int rr = 0; rr < 8; ++rr) {
        accR[rr]  += wv.x * av[rr];
        accZ[rr]  += wv.y * av[rr];
        accN1[rr] += wv.z * av[rr];
      }
    }
  }
  const float4 bb = ((const float4*)bias)[c];
  const float ow = OW[c];
  #pragma unroll
  for (int rr = 0; rr < 8; ++rr) {
    const float rg = sigmoid_f(accR[rr] + bb.x);
    const float zg = sigmoid_f(accZ[rr] + bb.y);
    const float nn = tanh_f(accN1[rr] + bb.z + rg * bb.w);
    gmat[(rh * 8 + rr) * 128 + c] = (1.f - zg) * nn * ow;
  }
  __syncthreads();
  if (t < 64) {
    const int r = t >> 2, part = t & 3;
    float s = 0.f;
    #pragma unroll
    for (int cc = 0; cc < 32; ++cc) s += gmat[r * 128 + part * 32 + cc];
    red[r * 4 + part] = s;
  }
  __syncthreads();
  if (t < 16) {
    const float s = red[t * 4] + red[t * 4 + 1] + red[t * 4 + 2] + red[t * 4 + 3];
    out[rowBase + t] = sigmoid_f(s + Ob[0]);
  }
}

// ---------------------------------------------------------------------------
extern "C" void kernel_launch(void* const* d_in, const int* in_sizes, int n_in,
                              void* d_out, int out_size, void* d_ws, size_t ws_size,
                              hipStream_t stream)
{
  (void)in_sizes; (void)n_in; (void)out_size; (void)ws_size;
  const float* towers = (const float*)d_in[0];
  const float* EnW1 = (const float*)d_in[1];
  const float* EnB1 = (const float*)d_in[2];
  const float* EnW2 = (const float*)d_in[3];
  const float* EnB2 = (const float*)d_in[4];
  const float* EeW1 = (const float*)d_in[5];
  const float* EeB1 = (const float*)d_in[6];
  const float* EeW2 = (const float*)d_in[7];
  const float* EeB2 = (const float*)d_in[8];
  const float* UWih = (const float*)d_in[9];
  const float* UWhh = (const float*)d_in[10];
  const float* UBih = (const float*)d_in[11];
  const float* UBhh = (const float*)d_in[12];
  const float* MWih = (const float*)d_in[13];
  const float* MWhh = (const float*)d_in[14];
  const float* MBih = (const float*)d_in[15];
  const float* MBhh = (const float*)d_in[16];
  const float* GWih = (const float*)d_in[17];
  const float* GWhh = (const float*)d_in[18];
  const float* GBih = (const float*)d_in[19];
  const float* GBhh = (const float*)d_in[20];
  const float* OW   = (const float*)d_in[21];
  const float* Ob   = (const float*)d_in[22];

  char* ws = (char*)d_ws;
  size_t off = 0;
  auto take = [&](size_t b) { void* p = ws + off; off = (off + b + 255) & ~(size_t)255; return p; };
  ush*   xh     = (ush*)take((size_t)32768 * 144 * 2);
  ush*   eh     = (ush*)take((size_t)262144 * 128 * 2);
  float* hsum   = (float*)take((size_t)4096 * 128 * 4);
  float* esum   = (float*)take((size_t)4096 * 128 * 4);
  ush*   WIHe   = (ush*)take((size_t)9 * 384 * 32 * 2);
  ush*   WTh    = (ush*)take((size_t)4 * 384 * 32 * 2);
  ush*   WTu    = (ush*)take((size_t)9 * 512 * 32 * 2);
  ush*   WBen1  = (ush*)take((size_t)128 * 32 * 2);
  ush*   WBen2  = (ush*)take((size_t)4 * 128 * 32 * 2);
  ush*   WBee1  = (ush*)take((size_t)128 * 32 * 2);
  ush*   WBee2  = (ush*)take((size_t)4 * 128 * 32 * 2);
  float* biasM  = (float*)take(512 * 4);
  float* biasU  = (float*)take(512 * 4);
  float* WT_G   = (float*)take((size_t)384 * 512 * 4);
  float* biasG  = (float*)take(512 * 4);

  prep_all<<<2646, 256, 0, stream>>>(
      towers, MWih, MWhh, UWih, UWhh, EnW1, EnW2, EeW1, EeW2,
      MBih, MBhh, UBih, UBhh, GWih, GWhh, GBih, GBhh,
      xh, WIHe, WTh, WTu, WBen1, WBen2, WBee1, WBee2,
      biasM, biasU, WT_G, biasG);

  // fused iterations: [enc + Ee | eh] -> edge GRU -> node GRU [-> sums]
  gn_iter<1, 0><<<512, 256, 0, stream>>>(eh, xh, WIHe, WTh, biasM, WTu, biasU,
                                         WBen1, EnB1, WBen2, EnB2,
                                         WBee1, EeB1, WBee2, EeB2, hsum, esum);
  gn_iter<0, 0><<<512, 256, 0, stream>>>(eh, xh, WIHe, WTh, biasM, WTu, biasU,
                                         WBen1, EnB1, WBen2, EnB2,
                                         WBee1, EeB1, WBee2, EeB2, hsum, esum);
  gn_iter<0, 1><<<512, 256, 0, stream>>>(eh, xh, WIHe, WTh, biasM, WTu, biasU,
                                         WBen1, EnB1, WBen2, EnB2,
                                         WBee1, EeB1, WBee2, EeB2, hsum, esum);

  gru_global_out<<<256, 256, 0, stream>>>(hsum, esum, WT_G, biasG, OW, Ob, (float*)d_out);
}

// Round 15
// 239.104 us; speedup vs baseline: 1.0526x; 1.0526x over previous
//
#include <hip/hip_runtime.h>
#include <hip/hip_bf16.h>

typedef __hip_bfloat16 bf16;
typedef unsigned short ush;
typedef short s16x8 __attribute__((ext_vector_type(8)));
typedef ush u16x4 __attribute__((ext_vector_type(4)));
typedef float f32x4 __attribute__((ext_vector_type(4)));

#define DEV __device__ __forceinline__

DEV float rcp_f(float x) { return __builtin_amdgcn_rcpf(x); }
DEV float sigmoid_f(float x) { return rcp_f(1.f + __expf(-x)); }
DEV float tanh_f(float x) { return 1.f - 2.f * rcp_f(__expf(2.f * x) + 1.f); }

DEV float u2f(ush u) { unsigned int v = ((unsigned int)u) << 16; float f; __builtin_memcpy(&f, &v, 4); return f; }
DEV ush f2u(float f) { bf16 h = __float2bfloat16(f); ush u; __builtin_memcpy(&u, &h, 2); return u; }

DEV f32x4 MFMA(s16x8 a, s16x8 b, f32x4 c) {
  return __builtin_amdgcn_mfma_f32_16x16x32_bf16(a, b, c, 0, 0, 0);
}

DEV s16x8 z8() {
  s16x8 v;
  for (int z = 0; z < 8; ++z) v[z] = 0;
  return v;
}

// swizzled element index within a [rows][32] bf16 chunk: 16B blocks XOR'd by (row>>1)&3
DEV int swz_idx(int row, int kk) { return row * 32 + (((kk >> 3) ^ ((row >> 1) & 3)) << 3) + (kk & 7); }
DEV int swz_blk(int row, int blk) { return row * 32 + ((blk ^ ((row >> 1) & 3)) << 3); }

// ---------------------------------------------------------------------------
// N=4096 graphs, K=8 nodes, n_in=14, H=128, k=3 iters. Inputs fp32.
// xh:  [32768][144] bf16 = [towers(14), pad(2), h(128)]
// eh:  iteration-carry only (rows g*64 + i*9+1).
// gn_iter<FIRST,LAST> (512 blocks x 8 graphs): per-iteration fusion (R13
// verified structure):
//   [FIRST: Ee MLP -> As_e] / [else: As_e from eh]
//   edge GRU (WIHe·xx^T 9ck + WTh·e^T 4ck, full-width BX staging, no inner
//   barriers) -> As_e in place (+eh if !LAST)
//   node GRU (BX staged once, 9 barrier-free MFMA rounds, WTu direct-global)
//   [LAST: per-block hsum/esum]
// Laws learned: per-iteration kernels only (3-iter loop spills ~0.5GB,
// R8/R11); 8-graph blocks (R12); do NOT fold enc into gn_iter<FIRST> — the
// co-compiled template instantiations share regalloc and ALL spill (R14:
// WRITE 36->67MB per dispatch). enc stays a separate kernel.
// ---------------------------------------------------------------------------

__global__ __launch_bounds__(256) void prep_all(
    const float* __restrict__ towers,
    const float* __restrict__ MWih, const float* __restrict__ MWhh,
    const float* __restrict__ UWih, const float* __restrict__ UWhh,
    const float* __restrict__ EnW1, const float* __restrict__ EnW2,
    const float* __restrict__ EeW1, const float* __restrict__ EeW2,
    const float* __restrict__ MBih, const float* __restrict__ MBhh,
    const float* __restrict__ UBih, const float* __restrict__ UBhh,
    const float* __restrict__ GWih, const float* __restrict__ GWhh,
    const float* __restrict__ GBih, const float* __restrict__ GBhh,
    ush* __restrict__ xh, ush* __restrict__ WIHe, ush* __restrict__ WTh,
    ush* __restrict__ WTu, ush* __restrict__ WBen1, ush* __restrict__ WBen2,
    ush* __restrict__ WBee1, ush* __restrict__ WBee2,
    float* __restrict__ biasM, float* __restrict__ biasU,
    float* __restrict__ WT_G, float* __restrict__ biasG)
{
  const int b = blockIdx.x, t = threadIdx.x;
  if (b < 512) {                        // xh towers: 4 elems/thread
    const int idx = b * 256 + t;        // 131072 threads
    const int row = idx >> 2, k0 = (idx & 3) * 4;
    u16x4 v;
    #pragma unroll
    for (int j = 0; j < 4; ++j) {
      const int kk = k0 + j;
      v[j] = f2u(kk < 14 ? towers[row * 14 + kk] : 0.f);
    }
    *(u16x4*)&xh[row * 144 + k0] = v;
  } else if (b < 944) {                 // WIHe: 9*384*32 linear (edge Wih)
    const int idx = (b - 512) * 256 + t;
    const int ck = idx / 12288, rem = idx % 12288, n = rem >> 5, kk = rem & 31;
    const int k = ck * 32 + kk;
    const int gate = n >> 7, c = n & 127;
    const int row = gate * 128 + c;
    int col = -1;
    if (k < 14)                    col = k;               // x_i
    else if (k >= 16 && k < 144)   col = 14 + (k - 16);   // h_i
    else if (k >= 144 && k < 158)  col = 142 + (k - 144); // x_j
    else if (k >= 160)             col = 156 + (k - 160); // h_j
    WIHe[idx] = f2u((col >= 0) ? MWih[row * 284 + col] : 0.f);
  } else if (b < 1136) {                // WTh: 4*384*32 linear
    const int idx = (b - 944) * 256 + t;
    const int ck = idx / 12288, rem = idx % 12288, n = rem >> 5, kk = rem & 31;
    const int g = n >> 7, c = n & 127;
    WTh[idx] = f2u(MWhh[(g * 128 + c) * 128 + ck * 32 + kk]);
  } else if (b < 1712) {                // WTu: 9*512*32 swizzled
    const int idx = (b - 1136) * 256 + t;
    const int ck = idx >> 14, n = (idx >> 5) & 511, kk = idx & 31;
    const int k = ck * 32 + kk, gate = n >> 7, c = n & 127;
    float w = 0.f;
    const int row = (gate == 0) ? c : (gate == 1) ? 128 + c : 256 + c;
    if (k < 160) {
      int col = -1;
      if (k < 16)        { if (k < 14) col = k; }
      else if (k < 144)  col = 14 + (k - 16);
      if (gate != 3 && col >= 0) w = UWih[row * 142 + col];
    } else {
      if (gate != 2) w = UWhh[row * 128 + (k - 160)];
    }
    WTu[ck * 16384 + swz_idx(n, kk)] = f2u(w);
  } else if (b < 1728) {                // WBen1: 128x32 linear
    const int idx = (b - 1712) * 256 + t;
    const int n = (idx >> 5) & 127, kk = idx & 31;
    WBen1[idx] = f2u(kk < 14 ? EnW1[n * 14 + kk] : 0.f);
  } else if (b < 1792) {                // WBen2: 4*128*32 linear
    const int idx = (b - 1728) * 256 + t;
    const int ck = idx >> 12, n = (idx >> 5) & 127, kk = idx & 31;
    WBen2[idx] = f2u(EnW2[n * 128 + ck * 32 + kk]);
  } else if (b < 1808) {                // WBee1: 128x32 pair linear
    const int idx = (b - 1792) * 256 + t;
    const int n = (idx >> 5) & 127, kk = idx & 31;
    int col = (kk < 16) ? (kk < 14 ? kk : -1) : (kk < 30 ? 14 + (kk - 16) : -1);
    WBee1[idx] = f2u(col >= 0 ? EeW1[n * 28 + col] : 0.f);
    (void)n;
  } else if (b < 1872) {                // WBee2: 4*128*32 linear
    const int idx = (b - 1808) * 256 + t;
    const int ck = idx >> 12, n = (idx >> 5) & 127, kk = idx & 31;
    WBee2[idx] = f2u(EeW2[n * 128 + ck * 32 + kk]);
  } else if (b < 1874) {                // biasM [4 gates][128]
    const int idx = (b - 1872) * 256 + t;
    const int g = idx >> 7, c = idx & 127;
    float v;
    if (g == 0)      v = MBih[c] + MBhh[c];
    else if (g == 1) v = MBih[128 + c] + MBhh[128 + c];
    else if (g == 2) v = MBih[256 + c];
    else             v = MBhh[256 + c];
    biasM[idx] = v;
  } else if (b < 1876) {                // biasU
    const int idx = (b - 1874) * 256 + t;
    const int g = idx >> 7, c = idx & 127;
    float v;
    if (g == 0)      v = UBih[c] + UBhh[c];
    else if (g == 1) v = UBih[128 + c] + UBhh[128 + c];
    else if (g == 2) v = UBih[256 + c];
    else             v = UBhh[256 + c];
    biasU[idx] = v;
  } else if (b < 2644) {                // WT_G interleaved fp32: 384*512
    const int idx = (b - 1876) * 256 + t;
    const int kc = idx >> 9, cg = (idx >> 2) & 127, gate = idx & 3;
    const int row = (gate == 0) ? cg : (gate == 1) ? cg + 128 : cg + 256;
    float v = 0.f;
    if (kc < 256) { if (gate != 3) v = GWih[row * 256 + kc]; }
    else          { if (gate != 2) v = GWhh[row * 128 + (kc - 256)]; }
    WT_G[idx] = v;
  } else {                              // biasG
    const int idx = (b - 2644) * 256 + t;
    const int cg = idx >> 2, gate = idx & 3;
    float v;
    if (gate == 0)      v = GBih[cg] + GBhh[cg];
    else if (gate == 1) v = GBih[cg + 128] + GBhh[cg + 128];
    else if (gate == 2) v = GBih[cg + 256];
    else                v = GBhh[cg + 256];
    biasG[idx] = v;
  }
}

// ---------------------------------------------------------------------------
// Node encoder (E_n MLP): 64 node-rows per block, writes h to xh.
// ---------------------------------------------------------------------------
__global__ __launch_bounds__(256, 2) void enc_en(
    ush* __restrict__ xh,
    const ush* __restrict__ WB1, const float* __restrict__ b1,
    const ush* __restrict__ WB2, const float* __restrict__ b2)
{
  __shared__ ush smem[9216];           // A1 [0,1024) | Z1 [1024,9216)
  ush* A1 = smem;
  ush* Z1 = smem + 1024;
  const int t = threadIdx.x, lane = t & 63, w = t >> 6;
  const int rowBase = blockIdx.x * 64;
  const int quad = lane >> 4, l15 = lane & 15;

  {
    const int gm = t >> 2, gb = t & 3, grow = rowBase + gm;
    s16x8 v = z8();
    if (gb < 2) v = *(const s16x8*)(xh + grow * 144 + gb * 8);
    *(s16x8*)&A1[swz_blk(gm, gb)] = v;
  }
  __syncthreads();

  s16x8 af[4];
  #pragma unroll
  for (int rt = 0; rt < 4; ++rt)
    af[rt] = *(const s16x8*)&A1[swz_blk(rt * 16 + l15, quad)];
  f32x4 acc1[4][2];
  #pragma unroll
  for (int rt = 0; rt < 4; ++rt)
    #pragma unroll
    for (int ct = 0; ct < 2; ++ct) {
      #pragma unroll
      for (int q = 0; q < 4; ++q) acc1[rt][ct][q] = 0.f;
    }
  #pragma unroll
  for (int ct = 0; ct < 2; ++ct) {
    const int n = w * 32 + ct * 16 + l15;
    const s16x8 bf = *(const s16x8*)&WB1[n * 32 + quad * 8];
    #pragma unroll
    for (int rt = 0; rt < 4; ++rt) acc1[rt][ct] = MFMA(af[rt], bf, acc1[rt][ct]);
  }
  #pragma unroll
  for (int ct = 0; ct < 2; ++ct) {
    const int col = w * 32 + ct * 16 + l15;
    const int kk = col & 31;
    #pragma unroll
    for (int rt = 0; rt < 4; ++rt) {
      #pragma unroll
      for (int q = 0; q < 4; ++q) {
        const int m = rt * 16 + quad * 4 + q;
        Z1[w * 2048 + swz_idx(m, kk)] = f2u(tanh_f(acc1[rt][ct][q] + b1[col]));
      }
    }
  }
  __syncthreads();

  f32x4 acc2[4][2];
  #pragma unroll
  for (int rt = 0; rt < 4; ++rt)
    #pragma unroll
    for (int ct = 0; ct < 2; ++ct) {
      #pragma unroll
      for (int q = 0; q < 4; ++q) acc2[rt][ct][q] = 0.f;
    }
  for (int ck2 = 0; ck2 < 4; ++ck2) {
    #pragma unroll
    for (int rt = 0; rt < 4; ++rt)
      af[rt] = *(const s16x8*)&Z1[ck2 * 2048 + swz_blk(rt * 16 + l15, quad)];
    #pragma unroll
    for (int ct = 0; ct < 2; ++ct) {
      const int n = w * 32 + ct * 16 + l15;
      const s16x8 bf = *(const s16x8*)&WB2[(ck2 * 128 + n) * 32 + quad * 8];
      #pragma unroll
      for (int rt = 0; rt < 4; ++rt) acc2[rt][ct] = MFMA(af[rt], bf, acc2[rt][ct]);
    }
  }

  #pragma unroll
  for (int ct = 0; ct < 2; ++ct) {
    const int col = w * 32 + ct * 16 + l15;
    #pragma unroll
    for (int rt = 0; rt < 4; ++rt) {
      #pragma unroll
      for (int q = 0; q < 4; ++q) {
        const int r = rt * 16 + quad * 4 + q;
        xh[(rowBase + r) * 144 + 16 + col] = f2u(tanh_f(acc2[rt][ct][q] + b2[col]));
      }
    }
  }
}

// ---------------------------------------------------------------------------
// Ee MLP on the (i,i+1) pairs -> e^0 into As_e (B-operand layout).
// SC: A1 [0,1024) | Z1 [1024,9216).
// ---------------------------------------------------------------------------
DEV void ee_body(ush* As_e, ush* SC, const ush* __restrict__ xh,
                 const ush* __restrict__ WB1, const float* __restrict__ b1,
                 const ush* __restrict__ WB2, const float* __restrict__ b2,
                 int G0, int t)
{
  ush* A1 = SC;
  ush* Z1 = SC + 1024;
  const int lane = t & 63, w = t >> 6;
  const int quad = lane >> 4, l15 = lane & 15;

  {
    const int gm = t >> 2, gb = t & 3;
    const int gg = gm >> 3, i = gm & 7;
    const int xi = (G0 + gg) * 8 + i;
    const int xj = (i < 7) ? xi + 1 : xi;
    const s16x8 v = (gb < 2) ? *(const s16x8*)(xh + xi * 144 + gb * 8)
                             : *(const s16x8*)(xh + xj * 144 + (gb - 2) * 8);
    *(s16x8*)&A1[swz_blk(gm, gb)] = v;
  }
  __syncthreads();

  s16x8 af[4];
  #pragma unroll
  for (int rt = 0; rt < 4; ++rt)
    af[rt] = *(const s16x8*)&A1[swz_blk(rt * 16 + l15, quad)];
  f32x4 acc1[4][2];
  #pragma unroll
  for (int rt = 0; rt < 4; ++rt)
    #pragma unroll
    for (int ct = 0; ct < 2; ++ct) {
      #pragma unroll
      for (int q = 0; q < 4; ++q) acc1[rt][ct][q] = 0.f;
    }
  #pragma unroll
  for (int ct = 0; ct < 2; ++ct) {
    const int n = w * 32 + ct * 16 + l15;
    const s16x8 bf = *(const s16x8*)&WB1[n * 32 + quad * 8];
    #pragma unroll
    for (int rt = 0; rt < 4; ++rt) acc1[rt][ct] = MFMA(af[rt], bf, acc1[rt][ct]);
  }
  #pragma unroll
  for (int ct = 0; ct < 2; ++ct) {
    const int col = w * 32 + ct * 16 + l15;
    const int kk = col & 31;
    #pragma unroll
    for (int rt = 0; rt < 4; ++rt) {
      #pragma unroll
      for (int q = 0; q < 4; ++q) {
        const int m = rt * 16 + quad * 4 + q;
        Z1[w * 2048 + swz_idx(m, kk)] = f2u(tanh_f(acc1[rt][ct][q] + b1[col]));
      }
    }
  }
  __syncthreads();

  f32x4 acc2[4][2];
  #pragma unroll
  for (int rt = 0; rt < 4; ++rt)
    #pragma unroll
    for (int ct = 0; ct < 2; ++ct) {
      #pragma unroll
      for (int q = 0; q < 4; ++q) acc2[rt][ct][q] = 0.f;
    }
  for (int ck2 = 0; ck2 < 4; ++ck2) {
    #pragma unroll
    for (int rt = 0; rt < 4; ++rt)
      af[rt] = *(const s16x8*)&Z1[ck2 * 2048 + swz_blk(rt * 16 + l15, quad)];
    #pragma unroll
    for (int ct = 0; ct < 2; ++ct) {
      const int n = w * 32 + ct * 16 + l15;
      const s16x8 bf = *(const s16x8*)&WB2[(ck2 * 128 + n) * 32 + quad * 8];
      #pragma unroll
      for (int rt = 0; rt < 4; ++rt) acc2[rt][ct] = MFMA(af[rt], bf, acc2[rt][ct]);
    }
  }
  #pragma unroll
  for (int ct = 0; ct < 2; ++ct) {
    const int col = w * 32 + ct * 16 + l15;
    #pragma unroll
    for (int rt = 0; rt < 4; ++rt) {
      #pragma unroll
      for (int q = 0; q < 4; ++q) {
        const int r = rt * 16 + quad * 4 + q;
        As_e[(col >> 5) * 2048 + swz_idx(r, col & 31)] = f2u(tanh_f(acc2[rt][ct][q] + b2[col]));
      }
    }
  }
}

// ---------------------------------------------------------------------------
// Edge GRU core: full-width xx staged to BX ONCE, then 9 MFMA rounds with no
// barriers; h phase from As_e; in-place As_e update; eh carry unless LAST.
// ---------------------------------------------------------------------------
template<int LAST>
DEV void edge_core(ush* As_e, ush* BX, ush* __restrict__ eh,
                   const ush* __restrict__ WIHe, const ush* __restrict__ WTh,
                   const float* __restrict__ biasM,
                   const ush* __restrict__ xh, int G0, int t)
{
  const int lane = t & 63, w = t >> 6;
  const int quad = lane >> 4, l15 = lane & 15;
  const int ko = quad * 8;

  f32x4 accR[2][4], accZ[2][4], accN1[2][4], accN2[2][4];
  #pragma unroll
  for (int mt = 0; mt < 2; ++mt)
    #pragma unroll
    for (int nt = 0; nt < 4; ++nt) {
      #pragma unroll
      for (int q = 0; q < 4; ++q) { accR[mt][nt][q] = 0.f; accZ[mt][nt][q] = 0.f; accN1[mt][nt][q] = 0.f; accN2[mt][nt][q] = 0.f; }
    }

  // stage ALL 9 xx chunks (K=288) into BX, one barrier
  {
    const int gm = t >> 2, gb = t & 3;
    const int gg = gm >> 3, i = gm & 7;
    const int xi = (G0 + gg) * 8 + i;
    const int xj = xi + ((i < 7) ? 1 : 0);
    #pragma unroll
    for (int ck = 0; ck < 9; ++ck) {
      const int k0 = ck * 32 + gb * 8;
      const s16x8 v = (k0 < 144) ? *(const s16x8*)(xh + xi * 144 + k0)
                                 : *(const s16x8*)(xh + xj * 144 + (k0 - 144));
      *(s16x8*)&BX[ck * 2048 + swz_blk(gm, gb)] = v;
    }
  }
  __syncthreads();

  // xx phase: 9 rounds, no barriers — compiler pipelines LDS + global loads
  #pragma unroll
  for (int ck = 0; ck < 9; ++ck) {
    s16x8 be[4];
    #pragma unroll
    for (int nt = 0; nt < 4; ++nt)
      be[nt] = *(const s16x8*)&BX[ck * 2048 + swz_blk(nt * 16 + l15, quad)];
    #pragma unroll
    for (int mt = 0; mt < 2; ++mt) {
      const int nb = w * 32 + mt * 16 + l15;
      const s16x8 aR = *(const s16x8*)&WIHe[(ck * 384 + nb) * 32 + ko];
      const s16x8 aZ = *(const s16x8*)&WIHe[(ck * 384 + 128 + nb) * 32 + ko];
      const s16x8 aN = *(const s16x8*)&WIHe[(ck * 384 + 256 + nb) * 32 + ko];
      #pragma unroll
      for (int nt = 0; nt < 4; ++nt) {
        accR[mt][nt]  = MFMA(aR, be[nt], accR[mt][nt]);
        accZ[mt][nt]  = MFMA(aZ, be[nt], accZ[mt][nt]);
        accN1[mt][nt] = MFMA(aN, be[nt], accN1[mt][nt]);
      }
    }
  }

  // h phase: K = 128 (4 chunks) from As_e, gates r, z, n2
  #pragma unroll
  for (int ck = 0; ck < 4; ++ck) {
    s16x8 be[4];
    #pragma unroll
    for (int nt = 0; nt < 4; ++nt)
      be[nt] = *(const s16x8*)&As_e[ck * 2048 + swz_blk(nt * 16 + l15, quad)];
    #pragma unroll
    for (int mt = 0; mt < 2; ++mt) {
      const int nb = w * 32 + mt * 16 + l15;
      const s16x8 aR = *(const s16x8*)&WTh[(ck * 384 + nb) * 32 + ko];
      const s16x8 aZ = *(const s16x8*)&WTh[(ck * 384 + 128 + nb) * 32 + ko];
      const s16x8 aN = *(const s16x8*)&WTh[(ck * 384 + 256 + nb) * 32 + ko];
      #pragma unroll
      for (int nt = 0; nt < 4; ++nt) {
        accR[mt][nt]  = MFMA(aR, be[nt], accR[mt][nt]);
        accZ[mt][nt]  = MFMA(aZ, be[nt], accZ[mt][nt]);
        accN2[mt][nt] = MFMA(aN, be[nt], accN2[mt][nt]);
      }
    }
  }

  __syncthreads();   // all h-phase As_e reads complete before in-place update

  // epilogue: biases + GRU; in-place As_e update (1:1 thread ownership),
  // eh carry-out for valid slots unless LAST.
  #pragma unroll
  for (int mt = 0; mt < 2; ++mt) {
    const int hc0 = w * 32 + mt * 16 + quad * 4;
    const int ck2 = hc0 >> 5, kkB = hc0 & 31;
    #pragma unroll
    for (int nt = 0; nt < 4; ++nt) {
      const int erow = nt * 16 + l15;
      const int gg = erow >> 3, i = erow & 7;
      ush* cell = &As_e[ck2 * 2048 + swz_blk(erow, kkB >> 3) + (kkB & 7)];
      const u16x4 hp4 = *(const u16x4*)cell;
      u16x4 ov;
      #pragma unroll
      for (int q = 0; q < 4; ++q) {
        const int c = hc0 + q;
        const float rg = sigmoid_f(accR[mt][nt][q] + biasM[c]);
        const float zg = sigmoid_f(accZ[mt][nt][q] + biasM[128 + c]);
        const float nn = tanh_f(accN1[mt][nt][q] + biasM[256 + c]
                                + rg * (accN2[mt][nt][q] + biasM[384 + c]));
        const float hp = u2f(hp4[q]);
        ov[q] = f2u(nn + zg * (hp - nn));
      }
      *(u16x4*)cell = ov;
      if (!LAST && i < 7)
        *(u16x4*)&eh[(size_t)((G0 + gg) * 64 + i * 9 + 1) * 128 + hc0] = ov;
    }
  }
}

// ---------------------------------------------------------------------------
// Node GRU: full 288-wide input staged to BX once, then 9 MFMA rounds with
// no barriers (WTu B direct-global); edges from As_e (LDS).
// ---------------------------------------------------------------------------
DEV void node_lds(const ush* As_e, ush* BX, ush* __restrict__ xh,
                  const ush* __restrict__ WT, const float* __restrict__ bias,
                  int rowBase, int t)
{
  constexpr int NCH = 9, XCH = 5;
  const int lane = t & 63, w = t >> 6;
  const int l15 = lane & 15, quad = lane >> 4;

  f32x4 accR[4][2], accZ[4][2], accN1[4][2], accN2[4][2];
  #pragma unroll
  for (int rt = 0; rt < 4; ++rt)
    #pragma unroll
    for (int s = 0; s < 2; ++s) {
      #pragma unroll
      for (int q = 0; q < 4; ++q) { accR[rt][s][q] = 0.f; accZ[rt][s][q] = 0.f; accN1[rt][s][q] = 0.f; accN2[rt][s][q] = 0.f; }
    }

  // stage ALL 9 input chunks into BX, one barrier
  {
    const int gm = t >> 2, gb = t & 3, grow = rowBase + gm;
    const int i = gm & 7;
    #pragma unroll
    for (int ck = 0; ck < NCH; ++ck) {
      const int k0 = ck * 32 + gb * 8;
      s16x8 v = z8();
      if (k0 < 16)       v = *(const s16x8*)(xh + grow * 144 + k0);
      else if (k0 < 144) {
        if (i < 7) {
          const int ke = k0 - 16;
          v = *(const s16x8*)&As_e[(ke >> 5) * 2048 + swz_blk(gm, (ke & 31) >> 3)];
        }
      } else if (k0 >= 160) {
        v = *(const s16x8*)(xh + grow * 144 + 16 + (k0 - 160));
      }
      *(s16x8*)&BX[ck * 2048 + swz_blk(gm, gb)] = v;
    }
  }
  __syncthreads();

  // 9 MFMA rounds, no barriers
  #pragma unroll
  for (int ck = 0; ck < NCH; ++ck) {
    const ush* Wc = WT + ck * 16384;
    s16x8 af[4];
    #pragma unroll
    for (int rt = 0; rt < 4; ++rt)
      af[rt] = *(const s16x8*)&BX[ck * 2048 + swz_blk(rt * 16 + l15, quad)];
    if (ck < XCH) {
      #pragma unroll
      for (int s = 0; s < 2; ++s) {
        const int nb = w * 32 + s * 16 + l15;
        const s16x8 bR = *(const s16x8*)&Wc[swz_blk(0 * 128 + nb, quad)];
        const s16x8 bZ = *(const s16x8*)&Wc[swz_blk(1 * 128 + nb, quad)];
        const s16x8 bN = *(const s16x8*)&Wc[swz_blk(2 * 128 + nb, quad)];
        #pragma unroll
        for (int rt = 0; rt < 4; ++rt) {
          accR[rt][s]  = MFMA(af[rt], bR, accR[rt][s]);
          accZ[rt][s]  = MFMA(af[rt], bZ, accZ[rt][s]);
          accN1[rt][s] = MFMA(af[rt], bN, accN1[rt][s]);
        }
      }
    } else {
      #pragma unroll
      for (int s = 0; s < 2; ++s) {
        const int nb = w * 32 + s * 16 + l15;
        const s16x8 bR = *(const s16x8*)&Wc[swz_blk(0 * 128 + nb, quad)];
        const s16x8 bZ = *(const s16x8*)&Wc[swz_blk(1 * 128 + nb, quad)];
        const s16x8 bN = *(const s16x8*)&Wc[swz_blk(3 * 128 + nb, quad)];
        #pragma unroll
        for (int rt = 0; rt < 4; ++rt) {
          accR[rt][s]  = MFMA(af[rt], bR, accR[rt][s]);
          accZ[rt][s]  = MFMA(af[rt], bZ, accZ[rt][s]);
          accN2[rt][s] = MFMA(af[rt], bN, accN2[rt][s]);
        }
      }
    }
  }

  #pragma unroll
  for (int s = 0; s < 2; ++s) {
    const int hcol = w * 32 + s * 16 + l15;
    const float bR = bias[hcol], bZ = bias[128 + hcol], bN1 = bias[256 + hcol], bN2 = bias[384 + hcol];
    #pragma unroll
    for (int rt = 0; rt < 4; ++rt) {
      #pragma unroll
      for (int q = 0; q < 4; ++q) {
        const int r = rt * 16 + quad * 4 + q;
        const int row = rowBase + r;
        const float hp = u2f(xh[row * 144 + 16 + hcol]);
        const float rg = sigmoid_f(accR[rt][s][q] + bR);
        const float zg = sigmoid_f(accZ[rt][s][q] + bZ);
        const float nn = tanh_f(accN1[rt][s][q] + bN1 + rg * (accN2[rt][s][q] + bN2));
        xh[row * 144 + 16 + hcol] = f2u(nn + zg * (hp - nn));
      }
    }
  }
}

// per-block readout: esum from As_e (final edges), hsum from xh (final h)
DEV void sums_body(const ush* As_e, const ush* __restrict__ xh,
                   float* __restrict__ hsum, float* __restrict__ esum,
                   int G0, int rowBase, int t)
{
  #pragma unroll
  for (int ii = 0; ii < 4; ++ii) {
    const int p = t + ii * 256;
    const int gg = p >> 7, hh = p & 127;
    float es = 0.f;
    #pragma unroll
    for (int i = 0; i < 7; ++i) {
      const int slot = gg * 8 + i;
      es += u2f(As_e[(hh >> 5) * 2048 + swz_idx(slot, hh & 31)]);
    }
    float hs = 0.f;
    #pragma unroll
    for (int i = 0; i < 8; ++i)
      hs += u2f(xh[(rowBase + gg * 8 + i) * 144 + 16 + hh]);
    hsum[(G0 + gg) * 128 + hh] = hs;
    esum[(G0 + gg) * 128 + hh] = es;
  }
}

// ---------------------------------------------------------------------------
// One fused GN iteration: [Ee MLP | eh load] -> edge GRU -> node GRU [-> sums]
// LDS: As_e 8KB + BX 18KB = 26KB.
// ---------------------------------------------------------------------------
template<int FIRST, int LAST>
__global__ __launch_bounds__(256, 2) void gn_iter(
    ush* __restrict__ eh, ush* __restrict__ xh,
    const ush* __restrict__ WIHe, const ush* __restrict__ WTh,
    const float* __restrict__ biasM,
    const ush* __restrict__ WTu, const float* __restrict__ biasU,
    const ush* __restrict__ WBee1, const float* __restrict__ bEe1,
    const ush* __restrict__ WBee2, const float* __restrict__ bEe2,
    float* __restrict__ hsum, float* __restrict__ esum)
{
  __shared__ ush smem[26624];          // As_e [0,8192) | BX [8192,26624)
  ush* As_e = smem;
  ush* BX   = smem + 8192;
  const int t = threadIdx.x;
  const int G0 = blockIdx.x * 8, rowBase = blockIdx.x * 64;

  if (FIRST) {
    ee_body(As_e, BX, xh, WBee1, bEe1, WBee2, bEe2, G0, t);
  } else {
    const int gm = t >> 2, gb = t & 3;
    const int gg = gm >> 3, i = gm & 7;
    const ush* src = eh + (size_t)((G0 + gg) * 64 + i * 9 + 1) * 128;
    #pragma unroll
    for (int ck = 0; ck < 4; ++ck) {
      s16x8 v = z8();
      if (i < 7) v = *(const s16x8*)(src + ck * 32 + gb * 8);
      *(s16x8*)&As_e[ck * 2048 + swz_blk(gm, gb)] = v;
    }
  }
  __syncthreads();

  edge_core<LAST>(As_e, BX, eh, WIHe, WTh, biasM, xh, G0, t);
  __syncthreads();

  node_lds(As_e, BX, xh, WTu, biasU, rowBase, t);

  if (LAST) {
    __syncthreads();
    sums_body(As_e, xh, hsum, esum, G0, rowBase, t);
  }
}

// global GRU (h_prev = 0) fused with output head: 16 graphs per block.
__global__ __launch_bounds__(256) void gru_global_out(
    const float* __restrict__ hsum, const float* __restrict__ esum,
    const float* __restrict__ WT, const float* __restrict__ bias,
    const float* __restrict__ OW, const float* __restrict__ Ob,
    float* __restrict__ out)
{
  constexpr int KT = 384;
  __shared__ float4 ATl4[KT * 4];
  __shared__ float4 Bl4[16 * 128];
  __shared__ float gmat[16 * 128];
  __shared__ float red[16 * 4];
  float* ATl = (float*)ATl4;
  const int t = threadIdx.x;
  const int rowBase = blockIdx.x * 16;
  for (int idx = t; idx < KT * 16; idx += 256) {
    const int kc = idx >> 4, r = idx & 15, grow = rowBase + r;
    float v = 0.f;
    if (kc < 128)      v = hsum[grow * 128 + kc];
    else if (kc < 256) v = esum[grow * 128 + (kc - 128)];
    ATl[idx] = v;
  }
  const int c = t & 127, rh = t >> 7;
  float accR[8], accZ[8], accN1[8];
  #pragma unroll
  for (int rr = 0; rr < 8; ++rr) { accR[rr] = 0.f; accZ[rr] = 0.f; accN1[rr] = 0.f; }
  const float4* WT4 = (const float4*)WT;
  for (int ck = 0; ck < 16; ++ck) {
    __syncthreads();
    #pragma unroll
    for (int ii = 0; ii < 8; ++ii) { const int idx = t + ii * 256; Bl4[idx] = WT4[ck * 2048 + idx]; }
    __syncthreads();
    const int kb = ck * 16;
    #pragma unroll
    for (int kcl = 0; kcl < 16; ++kcl) {
      const float4 wv = Bl4[kcl * 128 + c];
      const float4 a0 = ATl4[(kb + kcl) * 4 + rh * 2];
      const float4 a1 = ATl4[(kb + kcl) * 4 + rh * 2 + 1];
      const float av[8] = {a0.x, a0.y, a0.z, a0.w, a1.x, a1.y, a1.z, a1.w};
      #pragma unroll
      for (int rr = 0; rr < 8; ++rr) {
        accR[rr]  += wv.x * av[rr];
        accZ[rr]  += wv.y * av[rr];
        accN1[rr] += wv.z * av[rr];
      }
    }
  }
  const float4 bb = ((const float4*)bias)[c];
  const float ow = OW[c];
  #pragma unroll
  for (int rr = 0; rr < 8; ++rr) {
    const float rg = sigmoid_f(accR[rr] + bb.x);
    const float zg = sigmoid_f(accZ[rr] + bb.y);
    const float nn = tanh_f(accN1[rr] + bb.z + rg * bb.w);
    gmat[(rh * 8 + rr) * 128 + c] = (1.f - zg) * nn * ow;
  }
  __syncthreads();
  if (t < 64) {
    const int r = t >> 2, part = t & 3;
    float s = 0.f;
    #pragma unroll
    for (int cc = 0; cc < 32; ++cc) s += gmat[r * 128 + part * 32 + cc];
    red[r * 4 + part] = s;
  }
  __syncthreads();
  if (t < 16) {
    const float s = red[t * 4] + red[t * 4 + 1] + red[t * 4 + 2] + red[t * 4 + 3];
    out[rowBase + t] = sigmoid_f(s + Ob[0]);
  }
}

// ---------------------------------------------------------------------------
extern "C" void kernel_launch(void* const* d_in, const int* in_sizes, int n_in,
                              void* d_out, int out_size, void* d_ws, size_t ws_size,
                              hipStream_t stream)
{
  (void)in_sizes; (void)n_in; (void)out_size; (void)ws_size;
  const float* towers = (const float*)d_in[0];
  const float* EnW1 = (const float*)d_in[1];
  const float* EnB1 = (const float*)d_in[2];
  const float* EnW2 = (const float*)d_in[3];
  const float* EnB2 = (const float*)d_in[4];
  const float* EeW1 = (const float*)d_in[5];
  const float* EeB1 = (const float*)d_in[6];
  const float* EeW2 = (const float*)d_in[7];
  const float* EeB2 = (const float*)d_in[8];
  const float* UWih = (const float*)d_in[9];
  const float* UWhh = (const float*)d_in[10];
  const float* UBih = (const float*)d_in[11];
  const float* UBhh = (const float*)d_in[12];
  const float* MWih = (const float*)d_in[13];
  const float* MWhh = (const float*)d_in[14];
  const float* MBih = (const float*)d_in[15];
  const float* MBhh = (const float*)d_in[16];
  const float* GWih = (const float*)d_in[17];
  const float* GWhh = (const float*)d_in[18];
  const float* GBih = (const float*)d_in[19];
  const float* GBhh = (const float*)d_in[20];
  const float* OW   = (const float*)d_in[21];
  const float* Ob   = (const float*)d_in[22];

  char* ws = (char*)d_ws;
  size_t off = 0;
  auto take = [&](size_t b) { void* p = ws + off; off = (off + b + 255) & ~(size_t)255; return p; };
  ush*   xh     = (ush*)take((size_t)32768 * 144 * 2);
  ush*   eh     = (ush*)take((size_t)262144 * 128 * 2);
  float* hsum   = (float*)take((size_t)4096 * 128 * 4);
  float* esum   = (float*)take((size_t)4096 * 128 * 4);
  ush*   WIHe   = (ush*)take((size_t)9 * 384 * 32 * 2);
  ush*   WTh    = (ush*)take((size_t)4 * 384 * 32 * 2);
  ush*   WTu    = (ush*)take((size_t)9 * 512 * 32 * 2);
  ush*   WBen1  = (ush*)take((size_t)128 * 32 * 2);
  ush*   WBen2  = (ush*)take((size_t)4 * 128 * 32 * 2);
  ush*   WBee1  = (ush*)take((size_t)128 * 32 * 2);
  ush*   WBee2  = (ush*)take((size_t)4 * 128 * 32 * 2);
  float* biasM  = (float*)take(512 * 4);
  float* biasU  = (float*)take(512 * 4);
  float* WT_G   = (float*)take((size_t)384 * 512 * 4);
  float* biasG  = (float*)take(512 * 4);

  prep_all<<<2646, 256, 0, stream>>>(
      towers, MWih, MWhh, UWih, UWhh, EnW1, EnW2, EeW1, EeW2,
      MBih, MBhh, UBih, UBhh, GWih, GWhh, GBih, GBhh,
      xh, WIHe, WTh, WTu, WBen1, WBen2, WBee1, WBee2,
      biasM, biasU, WT_G, biasG);

  // node encoder
  enc_en<<<512, 256, 0, stream>>>(xh, WBen1, EnB1, WBen2, EnB2);

  // fused iterations: [Ee | eh] -> edge GRU -> node GRU [-> sums]
  gn_iter<1, 0><<<512, 256, 0, stream>>>(eh, xh, WIHe, WTh, biasM, WTu, biasU,
                                         WBee1, EeB1, WBee2, EeB2, hsum, esum);
  gn_iter<0, 0><<<512, 256, 0, stream>>>(eh, xh, WIHe, WTh, biasM, WTu, biasU,
                                         WBee1, EeB1, WBee2, EeB2, hsum, esum);
  gn_iter<0, 1><<<512, 256, 0, stream>>>(eh, xh, WIHe, WTh, biasM, WTu, biasU,
                                         WBee1, EeB1, WBee2, EeB2, hsum, esum);

  gru_global_out<<<256, 256, 0, stream>>>(hsum, esum, WT_G, biasG, OW, Ob, (float*)d_out);
}